// Round 1
// baseline (85.146 us; speedup 1.0000x reference)
//
#include <hip/hip_runtime.h>

constexpr int N  = 1024;
constexpr int BS = 32;
constexpr int FO = 128;

// ws layout: ws[0]=c1, ws[1]=c2, ws[2..33]=per-batch sum of x[b,:]
__global__ void prep_kernel(const float* __restrict__ W, const float* __restrict__ a,
                            float* __restrict__ ws) {
  int t = threadIdx.x;  // 64 threads
  float p1 = W[t] * a[t]       + W[t + 64] * a[t + 64];
  float p2 = W[t] * a[FO + t]  + W[t + 64] * a[FO + 64 + t];
#pragma unroll
  for (int o = 32; o > 0; o >>= 1) {
    p1 += __shfl_xor(p1, o);
    p2 += __shfl_xor(p2, o);
  }
  if (t == 0) { ws[0] = p1; ws[1] = p2; }
}

__global__ void sums_kernel(const float* __restrict__ x, float* __restrict__ ws) {
  int b = blockIdx.x;
  int t = threadIdx.x;  // 256 threads
  const float* xb = x + b * N;
  float p = xb[t] + xb[t + 256] + xb[t + 512] + xb[t + 768];
#pragma unroll
  for (int o = 32; o > 0; o >>= 1) p += __shfl_xor(p, o);
  __shared__ float sb[4];
  if ((t & 63) == 0) sb[t >> 6] = p;
  __syncthreads();
  if (t == 0) ws[2 + b] = sb[0] + sb[1] + sb[2] + sb[3];
}

// One wave per adjacency row i; blockIdx.y selects a group of 8 batches.
__global__ __launch_bounds__(64) void gat_main(
    const float* __restrict__ x, const int* __restrict__ adj,
    const float* __restrict__ W, const float* __restrict__ ws,
    float* __restrict__ out) {
  const int i    = blockIdx.x;
  const int lane = threadIdx.x;
  const float c1 = ws[0], c2 = ws[1];

  // adjacency flags for j = 4*lane + 256*k + m  (coalesced int4 loads)
  float adjf[16];
  const int4* arow = reinterpret_cast<const int4*>(adj + (size_t)i * N);
#pragma unroll
  for (int k = 0; k < 4; ++k) {
    int4 aq = arow[lane + 64 * k];
    adjf[k * 4 + 0] = aq.x > 0 ? 1.f : 0.f;
    adjf[k * 4 + 1] = aq.y > 0 ? 1.f : 0.f;
    adjf[k * 4 + 2] = aq.z > 0 ? 1.f : 0.f;
    adjf[k * 4 + 3] = aq.w > 0 ? 1.f : 0.f;
  }
  const float wlo = W[lane], whi = W[lane + 64];

  const int b0 = blockIdx.y * (BS / 4);
  for (int b = b0; b < b0 + BS / 4; ++b) {
    const float* xb = x + b * N;
    const float thr = -c1 * xb[i];   // keep j iff c2*x_j > thr (and adj)
    float Z = 0.f, Wm = 0.f;
    const float4* xrow = reinterpret_cast<const float4*>(xb);
#pragma unroll
    for (int k = 0; k < 4; ++k) {
      float4 xq = xrow[lane + 64 * k];
      float xv[4] = {xq.x, xq.y, xq.z, xq.w};
#pragma unroll
      for (int m = 0; m < 4; ++m) {
        float w = c2 * xv[m];
        float u = __expf(w);                       // base & max cancel in softmax
        float keep = (w > thr) ? adjf[k * 4 + m] : 0.f;
        float uu = u * keep;
        Z += uu;
        Wm = fmaf(uu, xv[m], Wm);
      }
    }
#pragma unroll
    for (int o = 32; o > 0; o >>= 1) {
      Z  += __shfl_xor(Z, o);
      Wm += __shfl_xor(Wm, o);
    }
    // empty active set -> softmax over all-NEG row = uniform -> mean(x[b,:])
    float t = (Z > 0.f) ? (Wm / Z) : (ws[2 + b] * (1.f / N));

    // out[b,i,f] = elu(t * W[f])
    float z0 = t * wlo, z1 = t * whi;
    float r0 = z0 > 0.f ? z0 : __expf(z0) - 1.f;
    float r1 = z1 > 0.f ? z1 : __expf(z1) - 1.f;
    float* orow = out + ((size_t)b * N + i) * FO;
    orow[lane]      = r0;
    orow[lane + 64] = r1;
  }
}

extern "C" void kernel_launch(void* const* d_in, const int* in_sizes, int n_in,
                              void* d_out, int out_size, void* d_ws, size_t ws_size,
                              hipStream_t stream) {
  const float* x   = (const float*)d_in[0];
  const int*   adj = (const int*)d_in[1];
  const float* W   = (const float*)d_in[4];
  const float* a   = (const float*)d_in[5];
  float* out = (float*)d_out;
  float* ws  = (float*)d_ws;

  hipLaunchKernelGGL(prep_kernel, dim3(1), dim3(64), 0, stream, W, a, ws);
  hipLaunchKernelGGL(sums_kernel, dim3(BS), dim3(256), 0, stream, x, ws);
  hipLaunchKernelGGL(gat_main, dim3(N, 4), dim3(64), 0, stream, x, adj, W, ws, out);
}

// Round 2
// 83.845 us; speedup vs baseline: 1.0155x; 1.0155x over previous
//
#include <hip/hip_runtime.h>

constexpr int N  = 1024;
constexpr int BS = 32;
constexpr int FO = 128;

// DPP-based wave64 sum, result broadcast to all lanes via readlane(63).
// update_dpp(old=0, src, ctrl, row_mask, bank_mask, bound_ctrl=true):
// lanes not written by the dpp op contribute old=0 to the add.
template <int ctrl, int rmask>
__device__ __forceinline__ float dpp_add(float x) {
  int y = __builtin_amdgcn_update_dpp(0, __float_as_int(x), ctrl, rmask, 0xf, true);
  return x + __int_as_float(y);
}

__device__ __forceinline__ float wave_sum_bcast(float x) {
  x = dpp_add<0x111, 0xf>(x);  // row_shr:1
  x = dpp_add<0x112, 0xf>(x);  // row_shr:2
  x = dpp_add<0x114, 0xf>(x);  // row_shr:4
  x = dpp_add<0x118, 0xf>(x);  // row_shr:8  -> lane15 of each row has row sum
  x = dpp_add<0x142, 0xa>(x);  // row_bcast:15 -> lane31 = rows0-1, lane63 = rows2-3
  x = dpp_add<0x143, 0xc>(x);  // row_bcast:31 -> lane63 = total
  return __int_as_float(__builtin_amdgcn_readlane(__float_as_int(x), 63));
}

// One wave per adjacency row i; blockIdx.y picks a group of 8 batches.
// Fully fused: c1/c2 and the empty-set fallback sum are computed in-wave.
__global__ __launch_bounds__(64) void gat_fused(
    const float* __restrict__ x, const int* __restrict__ adj,
    const float* __restrict__ W, const float* __restrict__ a,
    float* __restrict__ out) {
  const int i    = blockIdx.x;
  const int lane = threadIdx.x;

  // c1 = <W, a[0:128]>, c2 = <W, a[128:256]> — redundant per wave, ~100 cyc
  const float wl = W[lane], wh = W[lane + 64];
  const float c1 = wave_sum_bcast(wl * a[lane] + wh * a[lane + 64]);
  const float c2 = wave_sum_bcast(wl * a[FO + lane] + wh * a[FO + 64 + lane]);

  // epilogue covers f = 2*lane, 2*lane+1  -> one float2 store per lane
  const float2 w2 = reinterpret_cast<const float2*>(W)[lane];

  // adjacency flags for j = 4*(lane + 64k) + m   (coalesced int4 loads)
  float adjf[16];
  const int4* arow = reinterpret_cast<const int4*>(adj + (size_t)i * N);
#pragma unroll
  for (int k = 0; k < 4; ++k) {
    int4 aq = arow[lane + 64 * k];
    adjf[k * 4 + 0] = aq.x > 0 ? 1.f : 0.f;
    adjf[k * 4 + 1] = aq.y > 0 ? 1.f : 0.f;
    adjf[k * 4 + 2] = aq.z > 0 ? 1.f : 0.f;
    adjf[k * 4 + 3] = aq.w > 0 ? 1.f : 0.f;
  }

  const int b0 = blockIdx.y * (BS / 4);
  for (int b = b0; b < b0 + BS / 4; ++b) {
    const float* xb = x + b * N;
    const float thr = -c1 * xb[i];  // keep j iff c2*x_j > thr (and adj)
    float Z = 0.f, Wm = 0.f, S = 0.f;
    const float4* xrow = reinterpret_cast<const float4*>(xb);
#pragma unroll
    for (int k = 0; k < 4; ++k) {
      float4 xq = xrow[lane + 64 * k];
      float xv[4] = {xq.x, xq.y, xq.z, xq.w};
#pragma unroll
      for (int m = 0; m < 4; ++m) {
        float xj = xv[m];
        S += xj;                               // for the empty-set fallback
        float w = c2 * xj;
        float u = __expf(w);                   // base & max cancel in softmax
        float uu = ((w > thr) ? adjf[k * 4 + m] : 0.f) * u;
        Z += uu;
        Wm = fmaf(uu, xj, Wm);
      }
    }
    Z  = wave_sum_bcast(Z);
    Wm = wave_sum_bcast(Wm);
    S  = wave_sum_bcast(S);
    // empty active set -> softmax over all-NEG row = uniform -> mean(x[b,:])
    float t = (Z > 0.f) ? (Wm / Z) : (S * (1.f / N));

    // out[b,i,f] = elu(t * W[f])
    float z0 = t * w2.x, z1 = t * w2.y;
    float2 r;
    r.x = z0 > 0.f ? z0 : __expf(z0) - 1.f;
    r.y = z1 > 0.f ? z1 : __expf(z1) - 1.f;
    reinterpret_cast<float2*>(out + ((size_t)b * N + i) * FO)[lane] = r;
  }
}

extern "C" void kernel_launch(void* const* d_in, const int* in_sizes, int n_in,
                              void* d_out, int out_size, void* d_ws, size_t ws_size,
                              hipStream_t stream) {
  const float* x   = (const float*)d_in[0];
  const int*   adj = (const int*)d_in[1];
  const float* W   = (const float*)d_in[4];
  const float* a   = (const float*)d_in[5];
  float* out = (float*)d_out;

  hipLaunchKernelGGL(gat_fused, dim3(N, 4), dim3(64), 0, stream,
                     x, adj, W, a, out);
}